// Round 1
// 668.961 us; speedup vs baseline: 1.0334x; 1.0334x over previous
//
#include <hip/hip_runtime.h>

#define N_NODES 50000
#define N_EDGES 800000
#define D_IN    128
#define D_E     64
#define NH      4
#define F_TOT   128          // NH * D_OUT
#define NEG_SLOPE 0.2f

typedef __attribute__((ext_vector_type(8))) short short8;   // 8 bf16
typedef __attribute__((ext_vector_type(4))) float f32x4;

__device__ __forceinline__ short f2bf(float x) {            // RNE f32->bf16
    unsigned u = __float_as_uint(x);
    u += 0x7FFFu + ((u >> 16) & 1u);
    return (short)(u >> 16);
}

// ---------------------------------------------------------------------------
// K1: HT[n][f] = sum_k H[n][k] * W[f][k]   (fp32, -> workspace)
// kept fp32: HT feeds the output directly; accuracy budget spent on ET only.
// ---------------------------------------------------------------------------
__global__ __launch_bounds__(256) void k_node_transform(
    const float* __restrict__ H, const float* __restrict__ W,
    float* __restrict__ HT)
{
    __shared__ float wt[D_IN * F_TOT];   // wt[k*128+f] = W[f][k]
    const int tid = threadIdx.x;
    for (int i = tid; i < D_IN * F_TOT; i += 256) {
        const int f = i & 127, k = i >> 7;
        wt[k * F_TOT + f] = W[f * D_IN + k];
    }
    __syncthreads();

    const int l = tid & 63;
    const int w = tid >> 6;
    const int gwave  = blockIdx.x * 4 + w;
    const int nwaves = gridDim.x * 4;
    const int ngroups = N_NODES / 8;     // 6250, exact

    for (int grp = gwave; grp < ngroups; grp += nwaves) {
        const int g = grp * 8;
        float ax[8], ay[8];
#pragma unroll
        for (int j = 0; j < 8; ++j) { ax[j] = 0.f; ay[j] = 0.f; }

        for (int k4 = 0; k4 < D_IN / 4; ++k4) {
            float hv[8][4];
#pragma unroll
            for (int j = 0; j < 8; ++j)
                *(float4*)hv[j] = *(const float4*)&H[(size_t)(g + j) * D_IN + k4 * 4];
#pragma unroll
            for (int kk = 0; kk < 4; ++kk) {
                const float2 wk = *(const float2*)&wt[(k4 * 4 + kk) * F_TOT + 2 * l];
#pragma unroll
                for (int j = 0; j < 8; ++j) {
                    ax[j] = fmaf(wk.x, hv[j][kk], ax[j]);
                    ay[j] = fmaf(wk.y, hv[j][kk], ay[j]);
                }
            }
        }
#pragma unroll
        for (int j = 0; j < 8; ++j) {
            float2 r; r.x = ax[j]; r.y = ay[j];
            *(float2*)&HT[(size_t)(g + j) * F_TOT + 2 * l] = r;
        }
    }
}

// ---------------------------------------------------------------------------
// K2a: histogram of dst degrees
// ---------------------------------------------------------------------------
__global__ __launch_bounds__(256) void k_hist(
    const int* __restrict__ EI, int* __restrict__ deg)
{
    const int e = blockIdx.x * 256 + threadIdx.x;
    if (e < N_EDGES) atomicAdd(&deg[EI[N_EDGES + e]], 1);
}

// ---------------------------------------------------------------------------
// K2b: single-block exclusive scan of deg -> row_start[0..N], cursor copy
// ---------------------------------------------------------------------------
__global__ __launch_bounds__(1024) void k_scan(
    const int* __restrict__ deg, int* __restrict__ row_start,
    int* __restrict__ cursor)
{
    __shared__ int wsum[16];
    __shared__ int carry;
    const int tid = threadIdx.x;
    const int l = tid & 63;
    const int wv = tid >> 6;
    if (tid == 0) carry = 0;

    for (int base = 0; base < N_NODES; base += 1024) {
        __syncthreads();                       // [A] carry ready, wsum free
        const int cb = carry;
        const int i = base + tid;
        const int v = (i < N_NODES) ? deg[i] : 0;
        int x = v;                             // inclusive wave scan
#pragma unroll
        for (int off = 1; off < 64; off <<= 1) {
            int t = __shfl_up(x, off, 64);
            if (l >= off) x += t;
        }
        if (l == 63) wsum[wv] = x;
        __syncthreads();                       // [B] wsum ready
        int wave_off = 0;
        for (int k = 0; k < wv; ++k) wave_off += wsum[k];
        int tot = 0;
#pragma unroll
        for (int k = 0; k < 16; ++k) tot += wsum[k];
        const int excl = cb + wave_off + (x - v);
        if (i < N_NODES) { row_start[i] = excl; cursor[i] = excl; }
        __syncthreads();                       // [C] all read cb/wsum
        if (tid == 0) carry = cb + tot;
    }
    __syncthreads();
    if (tid == 0) row_start[N_NODES] = carry;
}

// ---------------------------------------------------------------------------
// K3: MFMA logit kernel (lane-per-edge layout). One wave = 16 edges.
//   Operand-swapped MFMA: D(16f x 16e) = We_tile(16f x 32k) @ E_tile^T(32k x 16e)
//     A-frag (We): A[m=lane&15][k=(lane>>4)*8+j]      (same bytes as old B-frag)
//     B-frag (E):  B[k=(lane>>4)*8+j][n=lane&15]      (same bytes as old A-frag)
//     D: col=lane&15 -> EDGE, row=(lane>>4)*4+reg -> feature ft*16+g4*4+reg
//   Each lane owns 32 features of ONE edge:
//     - HT gathers are 16 independent dwordx4 (vs 64 scalar dword)
//     - atomicAdd(cursor[dst]) hoisted to tile start (latency hidden)
//     - reduce = 2 shfl_xor steps (g4 axis) instead of 4
//     - wperm store = one dwordx4 per edge
//   We-fragments + att live in LDS to cap VGPRs (gather window needs 64).
// ---------------------------------------------------------------------------
__global__ __launch_bounds__(256, 3) void k_logits(
    const float* __restrict__ E, const int* __restrict__ EI,
    const float* __restrict__ We, const float* __restrict__ att,
    const float* __restrict__ HT,
    float* __restrict__ wperm, int* __restrict__ srcperm,
    int* __restrict__ cursor)
{
    __shared__ short8 s_bf[8][2][64];   // 16 KB: per-lane We fragments (bf16)
    __shared__ f32x4  s_att[8][4];      // 512 B: att[ft*16 + g4*4 .. +3]

    const int tid = threadIdx.x;
    const int l   = tid & 63;
    const int wv  = tid >> 6;
    const int r16 = l & 15;          // A: feature row   B/D: edge col
    const int g4  = l >> 4;          // k-chunk selector / D feature group

    if (wv == 0) {
#pragma unroll
        for (int ft = 0; ft < 8; ++ft) {
#pragma unroll
            for (int kc = 0; kc < 2; ++kc) {
                const float* wp = &We[(size_t)(ft * 16 + r16) * D_E + kc * 32 + g4 * 8];
                const f32x4 lo = *(const f32x4*)wp;
                const f32x4 hi = *(const f32x4*)(wp + 4);
                short8 b;
                b[0] = f2bf(lo[0]); b[1] = f2bf(lo[1]); b[2] = f2bf(lo[2]); b[3] = f2bf(lo[3]);
                b[4] = f2bf(hi[0]); b[5] = f2bf(hi[1]); b[6] = f2bf(hi[2]); b[7] = f2bf(hi[3]);
                s_bf[ft][kc][l] = b;
            }
        }
        if (l < 32) {
            const int ft = l >> 2, g = l & 3;
            s_att[ft][g] = *(const f32x4*)&att[ft * 16 + g * 4];
        }
    }
    __syncthreads();

    const int gwave  = blockIdx.x * 4 + wv;
    const int nwaves = gridDim.x * 4;
    const int ntiles = N_EDGES / 16;     // 50000, exact

    for (int t = gwave; t < ntiles; t += nwaves) {
        const int e0 = t * 16;
        const int e  = e0 + r16;                 // this lane's edge
        const int sr = EI[e];
        const int dr = EI[N_EDGES + e];

        // CSR slot: depends only on dst -> issue NOW, consume at tile end.
        int pos = 0;
        if (l < 16) pos = atomicAdd(&cursor[dr], 1);

        // HT gathers: 16 independent 16B loads (features ft*16+g4*4 .. +3)
        const float* hsp = &HT[(size_t)sr * F_TOT + g4 * 4];
        const float* hdp = &HT[(size_t)dr * F_TOT + g4 * 4];
        f32x4 hs4[8], hd4[8];
#pragma unroll
        for (int ft = 0; ft < 8; ++ft) {
            hs4[ft] = *(const f32x4*)(hsp + ft * 16);
            hd4[ft] = *(const f32x4*)(hdp + ft * 16);
        }

        // B-operand fragments from E (f32 -> bf16)
        short8 af[2];
#pragma unroll
        for (int kc = 0; kc < 2; ++kc) {
            const float* ep = &E[(size_t)e * D_E + kc * 32 + g4 * 8];
            const f32x4 lo = *(const f32x4*)ep;
            const f32x4 hi = *(const f32x4*)(ep + 4);
            short8 a;
            a[0] = f2bf(lo[0]); a[1] = f2bf(lo[1]); a[2] = f2bf(lo[2]); a[3] = f2bf(lo[3]);
            a[4] = f2bf(hi[0]); a[5] = f2bf(hi[1]); a[6] = f2bf(hi[2]); a[7] = f2bf(hi[3]);
            af[kc] = a;
        }

        float ph[4] = {0.f, 0.f, 0.f, 0.f};
#pragma unroll
        for (int ft = 0; ft < 8; ++ft) {
            f32x4 z = {0.f, 0.f, 0.f, 0.f};
            z = __builtin_amdgcn_mfma_f32_16x16x32_bf16(s_bf[ft][0][l], af[0], z, 0, 0, 0);
            const f32x4 acc =
                __builtin_amdgcn_mfma_f32_16x16x32_bf16(s_bf[ft][1][l], af[1], z, 0, 0, 0);
            const f32x4 at = s_att[ft][g4];
#pragma unroll
            for (int r = 0; r < 4; ++r) {
                float v = hs4[ft][r] + hd4[ft][r] + acc[r];
                v = v > 0.f ? v : NEG_SLOPE * v;
                ph[ft >> 1] = fmaf(v, at[r], ph[ft >> 1]);
            }
        }
        // reduce over the 4 g4-lanes sharing this edge (lanes l, l^16, l^32, l^48)
#pragma unroll
        for (int h = 0; h < 4; ++h) {
            ph[h] += __shfl_xor(ph[h], 16, 64);
            ph[h] += __shfl_xor(ph[h], 32, 64);
        }
        if (l < 16) {
            f32x4 w;
            w[0] = __expf(ph[0]); w[1] = __expf(ph[1]);
            w[2] = __expf(ph[2]); w[3] = __expf(ph[3]);
            *(f32x4*)&wperm[(size_t)4 * pos] = w;     // one 16B store per edge
            srcperm[pos] = sr;
        }
    }
}

// ---------------------------------------------------------------------------
// K4: aggregation. One wave per dst node; per 16-edge batch, ONE coalesced
// preload of srcperm (lanes 0-15) and wperm (all 64 lanes), distributed by
// shfl; 16 fully-unrolled independent HT[src] gathers in flight.
// ---------------------------------------------------------------------------
__global__ __launch_bounds__(256, 8) void k_aggregate(
    const float* __restrict__ HT, const float* __restrict__ wperm,
    const int* __restrict__ srcperm, const int* __restrict__ row_start,
    float* __restrict__ out)
{
    const int tid = threadIdx.x;
    const int l = tid & 63;
    const int wv = tid >> 6;
    const int n = blockIdx.x * 4 + wv;
    if (n >= N_NODES) return;
    const int h = l >> 4;
    const int beg = row_start[n];
    const int end = row_start[n + 1];

    float ax = 0.f, ay = 0.f, sw = 0.f;
    for (int base = beg; base < end; base += 16) {
        const int   svl = (l < 16 && base + l < end) ? srcperm[base + l] : 0;
        const float wvl = (4 * base + l < 4 * end) ? wperm[4 * base + l] : 0.f;
#pragma unroll
        for (int j = 0; j < 16; ++j) {
            const int   s = __shfl(svl, j, 64);
            const float w = __shfl(wvl, 4 * j + h, 64);
            const float2 hs = *(const float2*)&HT[(size_t)s * F_TOT + 2 * l];
            ax = fmaf(w, hs.x, ax);
            ay = fmaf(w, hs.y, ay);
            sw += w;                  // w==0 for padded slots
        }
    }
    const float inv = 1.f / (sw + 1e-16f);
    float2 r; r.x = ax * inv; r.y = ay * inv;
    *(float2*)&out[(size_t)n * F_TOT + 2 * l] = r;
}

extern "C" void kernel_launch(void* const* d_in, const int* in_sizes, int n_in,
                              void* d_out, int out_size, void* d_ws, size_t ws_size,
                              hipStream_t stream)
{
    const float* H   = (const float*)d_in[0];
    const int*   EI  = (const int*)d_in[1];
    const float* E   = (const float*)d_in[2];
    const float* W   = (const float*)d_in[3];
    const float* We  = (const float*)d_in[4];
    const float* att = (const float*)d_in[5];
    float* out = (float*)d_out;

    // workspace layout (~42.2 MB)
    float* HT        = (float*)d_ws;                          // 6.4M f32
    float* wperm     = HT + (size_t)N_NODES * F_TOT;          // 3.2M f32
    int*   srcperm   = (int*)(wperm + (size_t)N_EDGES * NH);  // 800k i32
    int*   deg       = srcperm + N_EDGES;                     // 50k
    int*   row_start = deg + N_NODES;                         // 50k+1
    int*   cursor    = row_start + N_NODES + 1;               // 50k

    hipMemsetAsync(deg, 0, N_NODES * sizeof(int), stream);

    k_hist<<<(N_EDGES + 255) / 256, 256, 0, stream>>>(EI, deg);
    k_scan<<<1, 1024, 0, stream>>>(deg, row_start, cursor);
    k_node_transform<<<512, 256, 0, stream>>>(H, W, HT);
    k_logits<<<2048, 256, 0, stream>>>(E, EI, We, att, HT,
                                       wperm, srcperm, cursor);
    k_aggregate<<<(N_NODES + 3) / 4, 256, 0, stream>>>(HT, wperm, srcperm,
                                                       row_start, out);
}